// Round 6
// baseline (193.209 us; speedup 1.0000x reference)
//
#include <hip/hip_runtime.h>
#include <float.h>

#define DIM 64
#define NCODES 512
#define ROWS_PB 64
#define NW 8
#define CPW 64   // codes per wave
#define G 32     // codes per accumulator group (acc[] must fully unroll)

// Prep: LDS-tile transpose emb (D,K)->ET (K,D) + ||e||^2 + zero loss slot.
__global__ __launch_bounds__(256) void vq_prep(const float* __restrict__ emb,
                                               float* __restrict__ et,
                                               float* __restrict__ norms,
                                               float* __restrict__ loss_slot) {
  __shared__ float T[64][65];
  const int tid = threadIdx.x;
  const int k0 = blockIdx.x * 64;
  if (blockIdx.x == 0 && tid == 0) loss_slot[0] = 0.0f;
#pragma unroll
  for (int j = 0; j < 16; ++j) {
    const int d = (tid >> 6) + j * 4;
    const int kl = tid & 63;
    T[d][kl] = emb[d * NCODES + k0 + kl];
  }
  __syncthreads();
#pragma unroll
  for (int j = 0; j < 4; ++j) {
    const int f = tid + j * 256;
    const int kl = f >> 4;
    const int d4 = (f & 15) << 2;
    float4 q;
    q.x = T[d4 + 0][kl]; q.y = T[d4 + 1][kl];
    q.z = T[d4 + 2][kl]; q.w = T[d4 + 3][kl];
    *(float4*)&et[(size_t)(k0 + kl) * DIM + d4] = q;
  }
  if (tid < 64) {
    float s = 0.0f;
#pragma unroll
    for (int d = 0; d < DIM; ++d) s = fmaf(T[d][tid], T[d][tid], s);
    norms[k0 + tid] = s;
  }
}

// Main: 512 thr = 8 waves; 64 rows/block (row = lane, shared by all waves);
// wave w scans codes [64w,64w+64) via 2 groups of 32 register ACCUMULATORS
// (not demotable, unlike a cached x-row copy — rounds 4/5 lesson).
// x staged direct-to-LDS via global_load_lds with XOR swizzle:
//   slot s (16B) holds x-tile float4 (row=s>>4, col=(s&15)^(row&7))
// -> DMA's forced linear layout still gives conflict-free stride-256B reads.
__global__ __launch_bounds__(512) void vq_main(const float* __restrict__ x,
                                               const float* __restrict__ et,
                                               const float* __restrict__ norms,
                                               float* __restrict__ out,
                                               float* __restrict__ loss,
                                               float lscale) {
  __shared__ __align__(16) float sx[ROWS_PB * DIM];  // 16 KB swizzled
  __shared__ float sbest[NW * 64];
  __shared__ int sidx[NW * 64];
  __shared__ int sfk[ROWS_PB];

  const int tid = threadIdx.x;
  const int lane = tid & 63;
  const int wid = tid >> 6;
  const int kbase = __builtin_amdgcn_readfirstlane(wid * CPW);

  // ---- swizzled direct-to-LDS staging: 16 KB, 2 wave-issues/wave ----
  {
    const float4* __restrict__ src =
        (const float4*)(x + (size_t)blockIdx.x * ROWS_PB * DIM);
#pragma unroll
    for (int j = 0; j < 2; ++j) {
      const int s = wid * 128 + j * 64 + lane;  // dest slot = base + lane (HW rule)
      const int r = s >> 4;
      const int q = (s & 15) ^ (r & 7);
      __builtin_amdgcn_global_load_lds(
          (const __attribute__((address_space(1))) void*)(src + (r * 16 + q)),
          (__attribute__((address_space(3))) void*)(sx + (wid * 128 + j * 64) * 4),
          16, 0, 0);
    }
  }
  __syncthreads();

  const float4* sx4 = (const float4*)sx;
  const int lx = lane & 7;
  float best = FLT_MAX;
  int bestk = kbase;
  float xn = 0.0f;

#pragma unroll 1
  for (int g = 0; g < CPW / G; ++g) {
    float acc[G];
#pragma unroll
    for (int t = 0; t < G; ++t) acc[t] = 0.0f;

#pragma unroll 1
    for (int c = 0; c < 4; ++c) {  // d-chunks of 16
      int sb = lane * 16;          // f4 slot base for row=lane
      asm volatile("" : "+v"(sb)); // opaque: no CSE across g/c, no demotion
      float xr[16];
#pragma unroll
      for (int i = 0; i < 4; ++i)
        *(float4*)(xr + 4 * i) = sx4[sb + ((c * 4 + i) ^ lx)];
#pragma unroll
      for (int i = 0; i < 16; ++i) asm volatile("" : "+v"(xr[i]));

      if (g == 0 && wid == 0) {  // wave-uniform; for the loss identity
#pragma unroll
        for (int i = 0; i < 16; ++i) xn = fmaf(xr[i], xr[i], xn);
      }
      // 32 codes x 16 dims: 512 fma vs 4 ds_read_b128 + 32 s_load(64B)
#pragma unroll
      for (int t = 0; t < G; ++t) {
        const float* __restrict__ e =
            et + (size_t)(kbase + g * G + t) * DIM + c * 16;
#pragma unroll
        for (int i = 0; i < 16; ++i) acc[t] = fmaf(xr[i], e[i], acc[t]);
      }
    }
#pragma unroll
    for (int t = 0; t < G; ++t) {
      const int k = kbase + g * G + t;
      const float dist = fmaf(acc[t], -2.0f, norms[k]);  // ||x||^2 dropped
      if (dist < best) { best = dist; bestk = k; }  // strict <: first-index ties
    }
  }

  sbest[tid] = best;
  sidx[tid] = bestk;
  __syncthreads();

  if (wid == 0) {
    // Combine 8 code groups in ascending-k order; strict < keeps lowest k
    float fb = sbest[lane];
    int fk = sidx[lane];
#pragma unroll
    for (int w = 1; w < NW; ++w) {
      const float b = sbest[w * 64 + lane];
      if (b < fb) { fb = b; fk = sidx[w * 64 + lane]; }
    }
    sfk[lane] = fk;
    // ||x-q||^2 = best_dist + ||x||^2 (xn computed in-register above)
    float lsum = fb + xn;
#pragma unroll
    for (int off = 32; off > 0; off >>= 1) lsum += __shfl_down(lsum, off, 64);
    if (lane == 0) atomicAdd(loss, lsum * lscale);
  }
  __syncthreads();

  // Distributed epilogue: gather winning code rows, coalesced float4 store
  {
    float* __restrict__ o = out + (size_t)blockIdx.x * ROWS_PB * DIM;
#pragma unroll
    for (int j = 0; j < 2; ++j) {
      const int f = tid + j * 512;
      const int r = f >> 4;
      const int c = (f & 15) << 2;
      const int k = sfk[r];
      *(float4*)&o[(size_t)r * DIM + c] = *(const float4*)&et[(size_t)k * DIM + c];
    }
  }
}

extern "C" void kernel_launch(void* const* d_in, const int* in_sizes, int n_in,
                              void* d_out, int out_size, void* d_ws, size_t ws_size,
                              hipStream_t stream) {
  const float* x = (const float*)d_in[0];    // (64,32,32,64) fp32
  const float* emb = (const float*)d_in[1];  // (64,512) fp32
  float* out = (float*)d_out;                // out (4194304) + loss (1)

  const int nrows = in_sizes[0] / DIM;       // 65536
  float* et = (float*)d_ws;                  // 512*64 floats = 128 KiB
  float* norms = et + NCODES * DIM;          // 512 floats
  float* loss = out + (out_size - 1);

  vq_prep<<<NCODES / 64, 256, 0, stream>>>(emb, et, norms, loss);

  const float lscale = 1.25f / (float)(nrows * DIM);  // (1+beta)/numel
  vq_main<<<nrows / ROWS_PB, 512, 0, stream>>>(x, et, norms, out, loss, lscale);
}

// Round 7
// 112.235 us; speedup vs baseline: 1.7215x; 1.7215x over previous
//
#include <hip/hip_runtime.h>
#include <float.h>

#define DIM 64
#define NCODES 512
#define ROWS_PB 256

typedef _Float16 half8 __attribute__((ext_vector_type(8)));
typedef float floatx4 __attribute__((ext_vector_type(4)));

// ws layout (float offsets):
//   et   fp32 [512][64]            @ 0      (32768 f)
//   norms fp32 [512]               @ 32768
//   ETh  f16 swz [8 chunk][512 k][8] @ 33280  (16384 f = 32768 halves)
//   ETl  f16 swz                    @ 49664
#define WS_NORMS 32768
#define WS_ETH   33280
#define WS_ETL   49664

// Prep: transpose emb (D,K) -> fp32 et (K,D); norms; f16 hi/lo tables in the
// swizzled [chunk][code] layout vq_main's LDS wants (so staging is a linear
// copy). Scaled lo split: el' = f16((e - f16(e)) * 2048) keeps lo normal-range.
__global__ __launch_bounds__(256) void vq_prep(const float* __restrict__ emb,
                                               float* __restrict__ ws,
                                               float* __restrict__ loss_slot) {
  __shared__ float T[64][65];
  const int tid = threadIdx.x;
  const int k0 = blockIdx.x * 64;
  if (blockIdx.x == 0 && tid == 0) loss_slot[0] = 0.0f;
#pragma unroll
  for (int j = 0; j < 16; ++j) {
    const int d = (tid >> 6) + j * 4;
    const int kl = tid & 63;
    T[d][kl] = emb[d * NCODES + k0 + kl];
  }
  __syncthreads();
  float* et = ws;
  float* norms = ws + WS_NORMS;
#pragma unroll
  for (int j = 0; j < 4; ++j) {  // fp32 transposed copy (epilogue gather src)
    const int f = tid + j * 256;
    const int kl = f >> 4;
    const int d4 = (f & 15) << 2;
    float4 q;
    q.x = T[d4 + 0][kl]; q.y = T[d4 + 1][kl];
    q.z = T[d4 + 2][kl]; q.w = T[d4 + 3][kl];
    *(float4*)&et[(size_t)(k0 + kl) * DIM + d4] = q;
  }
  if (tid < 64) {
    float s = 0.0f;
#pragma unroll
    for (int d = 0; d < DIM; ++d) s = fmaf(T[d][tid], T[d][tid], s);
    norms[k0 + tid] = s;
  }
  // f16 hi/lo swizzled: chunk h (8 dims) x code k; 1024 16B-chunks per block
  _Float16* eth = (_Float16*)(ws + WS_ETH);
  _Float16* etl = (_Float16*)(ws + WS_ETL);
#pragma unroll
  for (int i = 0; i < 4; ++i) {
    const int g = i * 256 + tid;        // 0..1023
    const int split = g >> 9;           // 0=hi 1=lo
    const int h = (g >> 6) & 7;         // dim chunk
    const int kl = g & 63;
    const int k = k0 + kl;
    half8 hv;
#pragma unroll
    for (int di = 0; di < 8; ++di) {
      const float v = T[h * 8 + di][kl];
      const _Float16 eh = (_Float16)v;
      const _Float16 el = (_Float16)((v - (float)eh) * 2048.0f);
      hv[di] = split ? el : eh;
    }
    *(half8*)((split ? etl : eth) + ((size_t)h * 512 + k) * 8) = hv;
  }
}

// Main: 512 thr = 8 waves x 32 rows (2 row-tiles), full 512 codes per wave.
// Distances via mfma_f32_16x16x32_f16 with scaled lo-split (err ~1e-5, same
// as the fp32 path that has had zero argmin flips for 5 rounds).
// A[m=lane&15][k=quad*8+j]; B[n=lane&15][k=quad*8+j]; D col=lane&15,
// row=quad*4+reg (guide-verified layouts).
__global__ __launch_bounds__(512, 1) void vq_main(const float* __restrict__ x,
                                                  const float* __restrict__ ws,
                                                  float* __restrict__ out,
                                                  float* __restrict__ loss,
                                                  float lscale) {
  __shared__ __align__(16) _Float16 sEh[8 * 512 * 8];  // 64 KB
  __shared__ __align__(16) _Float16 sEl[8 * 512 * 8];  // 64 KB
  __shared__ float snorm[NCODES];
  __shared__ int sfk[ROWS_PB];

  const float* __restrict__ et = ws;
  const float* __restrict__ norms = ws + WS_NORMS;
  const _Float16* __restrict__ gh = (const _Float16*)(ws + WS_ETH);
  const _Float16* __restrict__ gl = (const _Float16*)(ws + WS_ETL);

  const int tid = threadIdx.x;
  const int lane = tid & 63;
  const int wid = tid >> 6;
  const int col = lane & 15;
  const int quad = lane >> 4;

  // Stage ET f16 tables: linear 64KB+64KB copies, dest = uniform + lane*16 (HW rule)
#pragma unroll
  for (int j = 0; j < 8; ++j)
    __builtin_amdgcn_global_load_lds(
        (const __attribute__((address_space(1))) void*)(gh + ((size_t)j * 512 + tid) * 8),
        (__attribute__((address_space(3))) void*)(sEh + ((size_t)j * 512 + tid) * 8),
        16, 0, 0);
#pragma unroll
  for (int j = 0; j < 8; ++j)
    __builtin_amdgcn_global_load_lds(
        (const __attribute__((address_space(1))) void*)(gl + ((size_t)j * 512 + tid) * 8),
        (__attribute__((address_space(3))) void*)(sEl + ((size_t)j * 512 + tid) * 8),
        16, 0, 0);
  snorm[tid] = norms[tid];

  // A-frags: 2 row-tiles x 2 ksteps, hi + scaled-lo; exact ||x||^2 alongside
  const int wrow0 = blockIdx.x * ROWS_PB + wid * 32;
  half8 ah[2][2], al[2][2];
  float xn[2] = {0.0f, 0.0f};
#pragma unroll
  for (int rt = 0; rt < 2; ++rt) {
#pragma unroll
    for (int ks = 0; ks < 2; ++ks) {
      const float4* xp = (const float4*)x +
                         (size_t)(wrow0 + rt * 16 + col) * 16 + ks * 8 + quad * 2;
      const float4 f0 = xp[0], f1 = xp[1];
      const float f[8] = {f0.x, f0.y, f0.z, f0.w, f1.x, f1.y, f1.z, f1.w};
#pragma unroll
      for (int j = 0; j < 8; ++j) {
        const float v = f[j];
        xn[rt] = fmaf(v, v, xn[rt]);
        const _Float16 h = (_Float16)v;
        ah[rt][ks][j] = h;
        al[rt][ks][j] = (_Float16)((v - (float)h) * 2048.0f);
      }
    }
    xn[rt] += __shfl_xor(xn[rt], 16);  // sum the 4 quads holding this row
    xn[rt] += __shfl_xor(xn[rt], 32);
  }
  __syncthreads();  // drains global_load_lds (vmcnt) + snorm

  float best[2][4];
  int bk[2][4];
#pragma unroll
  for (int rt = 0; rt < 2; ++rt)
#pragma unroll
    for (int r = 0; r < 4; ++r) { best[rt][r] = FLT_MAX; bk[rt][r] = 0; }

#pragma unroll 2
  for (int ct = 0; ct < 32; ++ct) {  // 16-code tiles
    const int n0 = ct * 16;
    // B-frags: [chunk=ks*4+quad][code] -> stride-16B over col: 2-way banks (free)
    const half8 bh0 = *(const half8*)&sEh[((0 + quad) * 512 + n0 + col) * 8];
    const half8 bh1 = *(const half8*)&sEh[((4 + quad) * 512 + n0 + col) * 8];
    const half8 bl0 = *(const half8*)&sEl[((0 + quad) * 512 + n0 + col) * 8];
    const half8 bl1 = *(const half8*)&sEl[((4 + quad) * 512 + n0 + col) * 8];
    const float nk = snorm[n0 + col];
    const int k = n0 + col;  // this lane's code for all 4 regs
#pragma unroll
    for (int rt = 0; rt < 2; ++rt) {
      floatx4 hh = {0.f, 0.f, 0.f, 0.f}, cr = {0.f, 0.f, 0.f, 0.f};
      hh = __builtin_amdgcn_mfma_f32_16x16x32_f16(ah[rt][0], bh0, hh, 0, 0, 0);
      hh = __builtin_amdgcn_mfma_f32_16x16x32_f16(ah[rt][1], bh1, hh, 0, 0, 0);
      cr = __builtin_amdgcn_mfma_f32_16x16x32_f16(al[rt][0], bh0, cr, 0, 0, 0);
      cr = __builtin_amdgcn_mfma_f32_16x16x32_f16(al[rt][1], bh1, cr, 0, 0, 0);
      cr = __builtin_amdgcn_mfma_f32_16x16x32_f16(ah[rt][0], bl0, cr, 0, 0, 0);
      cr = __builtin_amdgcn_mfma_f32_16x16x32_f16(ah[rt][1], bl1, cr, 0, 0, 0);
#pragma unroll
      for (int r = 0; r < 4; ++r) {
        const float s = fmaf(cr[r], 4.8828125e-4f, hh[r]);  // hh + cr/2048
        const float dist = fmaf(s, -2.0f, nk);  // ||x||^2 dropped (argmin-inv)
        if (dist < best[rt][r]) { best[rt][r] = dist; bk[rt][r] = k; }
      }
    }
  }

  // Reduce over the 16 col-lanes (xor butterfly); tie -> smaller k (np.argmin)
#pragma unroll
  for (int off = 1; off < 16; off <<= 1) {
#pragma unroll
    for (int rt = 0; rt < 2; ++rt)
#pragma unroll
      for (int r = 0; r < 4; ++r) {
        const float ob = __shfl_xor(best[rt][r], off);
        const int ok = __shfl_xor(bk[rt][r], off);
        if (ob < best[rt][r] || (ob == best[rt][r] && ok < bk[rt][r])) {
          best[rt][r] = ob; bk[rt][r] = ok;
        }
      }
  }

  // Loss: ||x-q||^2 = best + ||x||^2 ; all lanes compute (shuffles need full wave)
  float ls = 0.0f;
#pragma unroll
  for (int rt = 0; rt < 2; ++rt)
#pragma unroll
    for (int r = 0; r < 4; ++r) {
      const int m = quad * 4 + r;                       // row within tile
      const float xnm = __shfl(xn[rt], (lane & 48) | m, 64);
      ls += best[rt][r] + xnm;
    }
  ls = (col == 0) ? ls : 0.0f;   // one copy per quad
  ls += __shfl_xor(ls, 16);
  ls += __shfl_xor(ls, 32);
  if (lane == 0) atomicAdd(loss, ls * lscale);

  if (col == 0) {
#pragma unroll
    for (int rt = 0; rt < 2; ++rt)
#pragma unroll
      for (int r = 0; r < 4; ++r)
        sfk[wid * 32 + rt * 16 + quad * 4 + r] = bk[rt][r];
  }
  __syncthreads();

  // Epilogue: gather winning fp32 code rows, fully coalesced
  {
    float* __restrict__ o = out + (size_t)blockIdx.x * ROWS_PB * DIM;
#pragma unroll
    for (int j = 0; j < 8; ++j) {
      const int f = tid + j * 512;   // 0..4095
      const int r = f >> 4;          // row 0..255
      const int c = (f & 15) << 2;   // col 0..60
      const int k = sfk[r];
      *(float4*)&o[(size_t)r * DIM + c] = *(const float4*)&et[(size_t)k * DIM + c];
    }
  }
}

extern "C" void kernel_launch(void* const* d_in, const int* in_sizes, int n_in,
                              void* d_out, int out_size, void* d_ws, size_t ws_size,
                              hipStream_t stream) {
  const float* x = (const float*)d_in[0];    // (64,32,32,64) fp32
  const float* emb = (const float*)d_in[1];  // (64,512) fp32
  float* out = (float*)d_out;                // out (4194304) + loss (1)

  const int nrows = in_sizes[0] / DIM;       // 65536
  float* ws = (float*)d_ws;                  // 264 KB used
  float* loss = out + (out_size - 1);

  vq_prep<<<NCODES / 64, 256, 0, stream>>>(emb, ws, loss);

  const float lscale = 1.25f / (float)(nrows * DIM);  // (1+beta)/numel
  vq_main<<<nrows / ROWS_PB, 512, 0, stream>>>(x, ws, out, loss, lscale);
}